// Round 3
// baseline (314.383 us; speedup 1.0000x reference)
//
#include <hip/hip_runtime.h>

// Collapse: out = P3@(M.T)^3 + 16c@(M.T)^2 + 4c@M.T + c
// Re-associated: out = Y1 @ (M^2).T + u
//   M  = Wzf @ Wsum (Wsum = sum_k Wz[k], fused into B staging)
//   c  = 4*((sum_k bz[k]) @ Wzf.T + bzf)
//   Y1 = P3 @ M.T + 16c ;  u = 4c @ M.T + c ;  P3[t] = sum of tree t's 64 leaves
// Dispatches: pool(1024) -> pre{M,c0}(160) -> stage2{M2,Y1,u}(512) -> out(256)

#define HD 512
#define LDA_T 34
#define LDB_T 68

struct GemmSmem {
    float As[2][32][LDA_T];
    float Bs[2][32][LDB_T];
};

// ---------------- tiled SGEMM: C[i0:+32, j0:+64] = A @ op(B) + bscale*bias --
// MODE 0: NN  MODE 1: NN with B = sum of 4 Wz slices  MODE 2: NT
template<int MODE>
__device__ __forceinline__
void gemm_tile(const float* __restrict__ A, const float* __restrict__ B,
               float* __restrict__ C, const float* __restrict__ bias,
               float bscale, int i0, int j0, GemmSmem& sm) {
    const int tid  = threadIdx.x;
    const int tx   = tid & 15, ty = tid >> 4;
    const int arow = tid >> 3, acol4 = (tid & 7) << 2;
    const int ntcol = tid & 63, ntkq = (tid >> 6) << 3;
    const int nncol4 = (tid & 15) << 2, nnk = tid >> 4;

    float4 apre, bpre0, bpre1;

    auto load_tiles = [&](int k0) {
        apre = *(const float4*)&A[(size_t)(i0 + arow) * HD + k0 + acol4];
        if (MODE == 2) {
            const float* bp = &B[(size_t)(j0 + ntcol) * HD + k0 + ntkq];
            bpre0 = *(const float4*)bp;
            bpre1 = *(const float4*)(bp + 4);
        } else if (MODE == 0) {
            bpre0 = *(const float4*)&B[(size_t)(k0 + nnk) * HD + j0 + nncol4];
            bpre1 = *(const float4*)&B[(size_t)(k0 + nnk + 16) * HD + j0 + nncol4];
        } else {
            const float* b0 = &B[(size_t)(k0 + nnk) * HD + j0 + nncol4];
            const float* b1 = &B[(size_t)(k0 + nnk + 16) * HD + j0 + nncol4];
            float4 s0 = *(const float4*)b0, s1 = *(const float4*)b1;
            #pragma unroll
            for (int q = 1; q < 4; ++q) {
                float4 t0 = *(const float4*)(b0 + q * 262144);
                float4 t1 = *(const float4*)(b1 + q * 262144);
                s0.x += t0.x; s0.y += t0.y; s0.z += t0.z; s0.w += t0.w;
                s1.x += t1.x; s1.y += t1.y; s1.z += t1.z; s1.w += t1.w;
            }
            bpre0 = s0; bpre1 = s1;
        }
    };
    auto store_tiles = [&](int buf) {
        sm.As[buf][acol4 + 0][arow] = apre.x;
        sm.As[buf][acol4 + 1][arow] = apre.y;
        sm.As[buf][acol4 + 2][arow] = apre.z;
        sm.As[buf][acol4 + 3][arow] = apre.w;
        if (MODE == 2) {
            sm.Bs[buf][ntkq + 0][ntcol] = bpre0.x;
            sm.Bs[buf][ntkq + 1][ntcol] = bpre0.y;
            sm.Bs[buf][ntkq + 2][ntcol] = bpre0.z;
            sm.Bs[buf][ntkq + 3][ntcol] = bpre0.w;
            sm.Bs[buf][ntkq + 4][ntcol] = bpre1.x;
            sm.Bs[buf][ntkq + 5][ntcol] = bpre1.y;
            sm.Bs[buf][ntkq + 6][ntcol] = bpre1.z;
            sm.Bs[buf][ntkq + 7][ntcol] = bpre1.w;
        } else {
            *(float4*)&sm.Bs[buf][nnk][nncol4]      = bpre0;
            *(float4*)&sm.Bs[buf][nnk + 16][nncol4] = bpre1;
        }
    };

    float acc[2][4] = {};
    load_tiles(0);
    store_tiles(0);
    __syncthreads();

    for (int t = 0; t < 16; ++t) {
        if (t < 15) load_tiles((t + 1) << 5);
        const int cur = t & 1;
        #pragma unroll
        for (int kk = 0; kk < 32; ++kk) {
            float2 av = *(const float2*)&sm.As[cur][kk][ty << 1];
            float4 bv = *(const float4*)&sm.Bs[cur][kk][tx << 2];
            acc[0][0] += av.x * bv.x; acc[0][1] += av.x * bv.y;
            acc[0][2] += av.x * bv.z; acc[0][3] += av.x * bv.w;
            acc[1][0] += av.y * bv.x; acc[1][1] += av.y * bv.y;
            acc[1][2] += av.y * bv.z; acc[1][3] += av.y * bv.w;
        }
        if (t < 15) {
            store_tiles(1 - cur);
            __syncthreads();
        }
    }

    float4 bv = make_float4(0.f, 0.f, 0.f, 0.f);
    if (bias) {
        float4 tb = *(const float4*)&bias[j0 + (tx << 2)];
        bv.x = bscale * tb.x; bv.y = bscale * tb.y;
        bv.z = bscale * tb.z; bv.w = bscale * tb.w;
    }
    #pragma unroll
    for (int r = 0; r < 2; ++r) {
        const int row = i0 + (ty << 1) + r;
        float4 o;
        o.x = acc[r][0] + bv.x; o.y = acc[r][1] + bv.y;
        o.z = acc[r][2] + bv.z; o.w = acc[r][3] + bv.w;
        *(float4*)&C[(size_t)row * HD + j0 + (tx << 2)] = o;
    }
}

// ---- Pool: one block per tree; fully contiguous 128 KB sweep per block ----
__global__ __launch_bounds__(256) void pool_kernel(const float* __restrict__ x,
                                                   float* __restrict__ P3) {
    __shared__ float4 red[128];
    const int tree = blockIdx.x, tid = threadIdx.x;
    const float4* xp = (const float4*)x + (size_t)tree * 8192 + tid;
    float4 a0 = make_float4(0.f, 0.f, 0.f, 0.f), a1 = a0;
    #pragma unroll
    for (int g = 0; g < 4; ++g) {
        float4 v[8];
        #pragma unroll
        for (int i = 0; i < 8; ++i) v[i] = xp[(size_t)(g * 8 + i) * 256];
        #pragma unroll
        for (int i = 0; i < 8; i += 2) {
            a0.x += v[i].x;     a0.y += v[i].y;
            a0.z += v[i].z;     a0.w += v[i].w;
            a1.x += v[i + 1].x; a1.y += v[i + 1].y;
            a1.z += v[i + 1].z; a1.w += v[i + 1].w;
        }
    }
    a0.x += a1.x; a0.y += a1.y; a0.z += a1.z; a0.w += a1.w;
    if (tid >= 128) red[tid - 128] = a0;
    __syncthreads();
    if (tid < 128) {
        float4 b = red[tid];
        a0.x += b.x; a0.y += b.y; a0.z += b.z; a0.w += b.w;
        ((float4*)P3)[tree * 128 + tid] = a0;  // thread t holds col4 = t (t<128)
    }
}

// ---- Pre: [0,128) M = Wzf@Wsum | [128,160) c0, wave-per-4-outputs ----
__global__ __launch_bounds__(256) void pre_kernel(
        const float* __restrict__ Wz, const float* __restrict__ Wzf,
        const float* __restrict__ bz, const float* __restrict__ bzf,
        float* __restrict__ M, float* __restrict__ c0) {
    __shared__ GemmSmem sm;
    const int b = blockIdx.x, tid = threadIdx.x;
    if (b < 128) {
        gemm_tile<1>(Wzf, Wz, M, nullptr, 0.f, (b >> 3) << 5, (b & 7) << 6, sm);
    } else {
        const int bb = b - 128, wave = tid >> 6, lane = tid & 63;
        const int hb = lane << 3;  // 8 floats per lane
        float4 s0 = *(const float4*)&bz[hb];
        float4 s1 = *(const float4*)&bz[hb + 4];
        #pragma unroll
        for (int q = 1; q < 4; ++q) {
            float4 t0 = *(const float4*)&bz[q * HD + hb];
            float4 t1 = *(const float4*)&bz[q * HD + hb + 4];
            s0.x += t0.x; s0.y += t0.y; s0.z += t0.z; s0.w += t0.w;
            s1.x += t1.x; s1.y += t1.y; s1.z += t1.z; s1.w += t1.w;
        }
        #pragma unroll
        for (int q = 0; q < 4; ++q) {
            const int j = bb * 16 + wave * 4 + q;
            const float4* wr = (const float4*)&Wzf[(size_t)j * HD + hb];
            float4 w0 = wr[0], w1 = wr[1];
            float p = w0.x * s0.x + w0.y * s0.y + w0.z * s0.z + w0.w * s0.w
                    + w1.x * s1.x + w1.y * s1.y + w1.z * s1.z + w1.w * s1.w;
            #pragma unroll
            for (int off = 32; off > 0; off >>= 1) p += __shfl_down(p, off);
            if (lane == 0) c0[j] = 4.f * (p + bzf[j]);
        }
    }
}

// ---- Stage2: [0,128) M2=M@M | [128,384) Y1=P3@M.T+16c | [384,512) u ----
__global__ __launch_bounds__(256) void k_stage2(
        const float* __restrict__ M, const float* __restrict__ P3,
        const float* __restrict__ c0,
        float* __restrict__ M2, float* __restrict__ Y1, float* __restrict__ u) {
    __shared__ GemmSmem sm;
    const int b = blockIdx.x, tid = threadIdx.x;
    if (b < 128) {
        gemm_tile<0>(M, M, M2, nullptr, 0.f, (b >> 3) << 5, (b & 7) << 6, sm);
    } else if (b < 384) {
        const int bb = b - 128;
        gemm_tile<2>(P3, M, Y1, c0, 16.f, (bb >> 3) << 5, (bb & 7) << 6, sm);
    } else {
        const int bb = b - 384, wave = tid >> 6, lane = tid & 63;
        const int j = bb * 4 + wave, hb = lane << 3;
        const float4* mr = (const float4*)&M[(size_t)j * HD + hb];
        const float4* cr = (const float4*)&c0[hb];
        float4 m0 = mr[0], m1 = mr[1], q0 = cr[0], q1 = cr[1];
        float p = m0.x * q0.x + m0.y * q0.y + m0.z * q0.z + m0.w * q0.w
                + m1.x * q1.x + m1.y * q1.y + m1.z * q1.z + m1.w * q1.w;
        #pragma unroll
        for (int off = 32; off > 0; off >>= 1) p += __shfl_down(p, off);
        if (lane == 0) u[j] = 4.f * p + c0[j];
    }
}

// ---- Out: out = Y1 @ (M2).T + u ----
__global__ __launch_bounds__(256) void k_stage3(
        const float* __restrict__ Y1, const float* __restrict__ M2,
        const float* __restrict__ u, float* __restrict__ out) {
    __shared__ GemmSmem sm;
    const int b = blockIdx.x;
    gemm_tile<2>(Y1, M2, out, u, 1.f, (b >> 3) << 5, (b & 7) << 6, sm);
}

extern "C" void kernel_launch(void* const* d_in, const int* in_sizes, int n_in,
                              void* d_out, int out_size, void* d_ws, size_t ws_size,
                              hipStream_t stream) {
    const float* x   = (const float*)d_in[0];
    const float* Wz  = (const float*)d_in[1];
    const float* bz  = (const float*)d_in[2];
    const float* Wzf = (const float*)d_in[3];
    const float* bzf = (const float*)d_in[4];
    float* out = (float*)d_out;

    float* ws = (float*)d_ws;
    float* P3 = ws;                 // 1024*512
    float* Y1 = ws + 524288;        // 1024*512
    float* M  = ws + 1048576;       // 512*512
    float* M2 = ws + 1310720;       // 512*512
    float* c0 = ws + 1572864;       // 512
    float* u  = ws + 1573376;       // 512

    hipLaunchKernelGGL(pool_kernel, dim3(1024), dim3(256), 0, stream, x, P3);
    hipLaunchKernelGGL(pre_kernel,  dim3(160),  dim3(256), 0, stream,
                       Wz, Wzf, bz, bzf, M, c0);
    hipLaunchKernelGGL(k_stage2,    dim3(512),  dim3(256), 0, stream,
                       M, P3, c0, M2, Y1, u);
    hipLaunchKernelGGL(k_stage3,    dim3(256),  dim3(256), 0, stream,
                       Y1, M2, u, out);
}

// Round 4
// 296.559 us; speedup vs baseline: 1.0601x; 1.0601x over previous
//
#include <hip/hip_runtime.h>

// Collapse: out = P3@(M.T)^3 + 16c@(M.T)^2 + 4c@M.T + c
// Re-associated: out = Y1 @ (M^2).T + u
//   M  = Wzf @ Wsum (Wsum = sum_k Wz[k], fused into B staging, MODE 1)
//   c  = 4*((sum_k bz[k]) @ Wzf.T + bzf)
//   Y1 = P3 @ M.T + 16c ;  u = 4c @ M.T + c ;  P3[t] = sum of tree t's 64 leaves
// Dispatches: D1{M, pool, c0}(1216) -> D2{Y1, M2, u}(320) -> D3{out}(128)

#define HD 512
#define LDT 68   // LDS row stride (floats): 16B-aligned, bank-clean (proved below)

struct GemmSmem {
    float As[2][32][LDT];   // 17408 B
    float Bs[2][32][LDT];   // 17408 B  -> 34816 B total, 4 blocks/CU
};

// ---- tiled SGEMM: C[i0:+64, j0:+64] = A @ op(B) + bscale*bias ----
// MODE 0: NN   MODE 1: NN with B = sum of 4 Wz slices   MODE 2: NT
// 256 threads, 4x4 microtile, KT=32 double-buffered, ONE barrier per k-tile:
// stores at iter t target buf[(t+1)&1], whose readers finished at the barrier
// ending iter t-1; visibility for compute t+1 is the barrier ending iter t.
template<int MODE>
__device__ __forceinline__
void gemm_tile(const float* __restrict__ A, const float* __restrict__ B,
               float* __restrict__ C, const float* __restrict__ bias,
               float bscale, int i0, int j0, GemmSmem& sm) {
    const int tid  = threadIdx.x;
    const int tx   = tid & 15, ty = tid >> 4;          // 4x4 microtile coords
    const int arow = tid >> 2, akq = (tid & 3) << 2;   // A / NT-B staging
    const int bk   = tid >> 4, bc4 = (tid & 15) << 2;  // NN-B staging

    float4 ap0, ap1, bp0, bp1;

    auto load_tiles = [&](int k0) {
        const float* ar = &A[(size_t)(i0 + arow) * HD + k0 + akq];
        ap0 = *(const float4*)ar;
        ap1 = *(const float4*)(ar + 16);
        if (MODE == 2) {
            const float* br = &B[(size_t)(j0 + arow) * HD + k0 + akq];
            bp0 = *(const float4*)br;
            bp1 = *(const float4*)(br + 16);
        } else if (MODE == 0) {
            bp0 = *(const float4*)&B[(size_t)(k0 + bk) * HD + j0 + bc4];
            bp1 = *(const float4*)&B[(size_t)(k0 + bk + 16) * HD + j0 + bc4];
        } else {
            const float* b0 = &B[(size_t)(k0 + bk) * HD + j0 + bc4];
            const float* b1 = b0 + 16 * HD;
            float4 s0 = *(const float4*)b0, s1 = *(const float4*)b1;
            #pragma unroll
            for (int q = 1; q < 4; ++q) {
                float4 t0 = *(const float4*)(b0 + q * 262144);
                float4 t1 = *(const float4*)(b1 + q * 262144);
                s0.x += t0.x; s0.y += t0.y; s0.z += t0.z; s0.w += t0.w;
                s1.x += t1.x; s1.y += t1.y; s1.z += t1.z; s1.w += t1.w;
            }
            bp0 = s0; bp1 = s1;
        }
    };
    // A scatter banks: addr=(akq+i)*68+arow -> bank (4*(akq+i)+arow)&31; per
    // wave arow 0..15, 4*akq in {0,16,32,48}: all 32 banks hit once. Clean.
    auto store_tiles = [&](int buf) {
        sm.As[buf][akq + 0][arow]  = ap0.x;
        sm.As[buf][akq + 1][arow]  = ap0.y;
        sm.As[buf][akq + 2][arow]  = ap0.z;
        sm.As[buf][akq + 3][arow]  = ap0.w;
        sm.As[buf][akq + 16][arow] = ap1.x;
        sm.As[buf][akq + 17][arow] = ap1.y;
        sm.As[buf][akq + 18][arow] = ap1.z;
        sm.As[buf][akq + 19][arow] = ap1.w;
        if (MODE == 2) {
            sm.Bs[buf][akq + 0][arow]  = bp0.x;
            sm.Bs[buf][akq + 1][arow]  = bp0.y;
            sm.Bs[buf][akq + 2][arow]  = bp0.z;
            sm.Bs[buf][akq + 3][arow]  = bp0.w;
            sm.Bs[buf][akq + 16][arow] = bp1.x;
            sm.Bs[buf][akq + 17][arow] = bp1.y;
            sm.Bs[buf][akq + 18][arow] = bp1.z;
            sm.Bs[buf][akq + 19][arow] = bp1.w;
        } else {
            *(float4*)&sm.Bs[buf][bk][bc4]      = bp0;
            *(float4*)&sm.Bs[buf][bk + 16][bc4] = bp1;
        }
    };

    float acc[4][4] = {};
    load_tiles(0);
    store_tiles(0);
    __syncthreads();

    for (int t = 0; t < 16; ++t) {
        if (t < 15) load_tiles((t + 1) << 5);   // global prefetch, hidden by 512 FMAs
        const int cur = t & 1;
        #pragma unroll
        for (int kk = 0; kk < 32; ++kk) {
            float4 av = *(const float4*)&sm.As[cur][kk][ty << 2]; // 4 distinct, bcast
            float4 bv = *(const float4*)&sm.Bs[cur][kk][tx << 2]; // 2-way banks: free
            float aa[4] = {av.x, av.y, av.z, av.w};
            float bb[4] = {bv.x, bv.y, bv.z, bv.w};
            #pragma unroll
            for (int i = 0; i < 4; ++i)
                #pragma unroll
                for (int j = 0; j < 4; ++j)
                    acc[i][j] += aa[i] * bb[j];
        }
        if (t < 15) {
            store_tiles(1 - cur);
            __syncthreads();
        }
    }

    float4 bv = make_float4(0.f, 0.f, 0.f, 0.f);
    if (bias) {
        float4 tb = *(const float4*)&bias[j0 + (tx << 2)];
        bv.x = bscale * tb.x; bv.y = bscale * tb.y;
        bv.z = bscale * tb.z; bv.w = bscale * tb.w;
    }
    #pragma unroll
    for (int r = 0; r < 4; ++r) {
        const int row = i0 + (ty << 2) + r;
        float4 o;
        o.x = acc[r][0] + bv.x; o.y = acc[r][1] + bv.y;
        o.z = acc[r][2] + bv.z; o.w = acc[r][3] + bv.w;
        *(float4*)&C[(size_t)row * HD + j0 + (tx << 2)] = o;
    }
}

// ---- pool body: one block per tree, fully contiguous 128 KB sweep ----
__device__ __forceinline__
void pool_body(const float* __restrict__ x, float* __restrict__ P3,
               int tree, float4* red) {
    const int tid = threadIdx.x;
    const float4* xp = (const float4*)x + (size_t)tree * 8192 + tid;
    float4 a0 = make_float4(0.f, 0.f, 0.f, 0.f), a1 = a0;
    #pragma unroll
    for (int g = 0; g < 4; ++g) {
        float4 v[8];
        #pragma unroll
        for (int i = 0; i < 8; ++i) v[i] = xp[(size_t)(g * 8 + i) * 256];
        #pragma unroll
        for (int i = 0; i < 8; i += 2) {
            a0.x += v[i].x;     a0.y += v[i].y;
            a0.z += v[i].z;     a0.w += v[i].w;
            a1.x += v[i + 1].x; a1.y += v[i + 1].y;
            a1.z += v[i + 1].z; a1.w += v[i + 1].w;
        }
    }
    a0.x += a1.x; a0.y += a1.y; a0.z += a1.z; a0.w += a1.w;
    if (tid >= 128) red[tid - 128] = a0;
    __syncthreads();
    if (tid < 128) {
        float4 b = red[tid];
        a0.x += b.x; a0.y += b.y; a0.z += b.z; a0.w += b.w;
        ((float4*)P3)[tree * 128 + tid] = a0;
    }
}

// ---- D1: [0,64) M = Wzf@Wsum | [64,1088) pool | [1088,1216) c0 ----
__global__ __launch_bounds__(256) void k_stage1(
        const float* __restrict__ x, const float* __restrict__ Wz,
        const float* __restrict__ Wzf, const float* __restrict__ bz,
        const float* __restrict__ bzf,
        float* __restrict__ P3, float* __restrict__ M, float* __restrict__ c0) {
    __shared__ GemmSmem sm;
    const int b = blockIdx.x, tid = threadIdx.x;
    if (b < 64) {
        gemm_tile<1>(Wzf, Wz, M, nullptr, 0.f, (b >> 3) << 6, (b & 7) << 6, sm);
    } else if (b < 1088) {
        pool_body(x, P3, b - 64, (float4*)&sm);
    } else {
        const int j = (b - 1088) * 4 + (tid >> 6);  // one output per wave
        const int lane = tid & 63, hb = lane << 3;
        float4 s0 = *(const float4*)&bz[hb];
        float4 s1 = *(const float4*)&bz[hb + 4];
        #pragma unroll
        for (int q = 1; q < 4; ++q) {
            float4 t0 = *(const float4*)&bz[q * HD + hb];
            float4 t1 = *(const float4*)&bz[q * HD + hb + 4];
            s0.x += t0.x; s0.y += t0.y; s0.z += t0.z; s0.w += t0.w;
            s1.x += t1.x; s1.y += t1.y; s1.z += t1.z; s1.w += t1.w;
        }
        const float4* wr = (const float4*)&Wzf[(size_t)j * HD + hb];
        float4 w0 = wr[0], w1 = wr[1];
        float p = w0.x * s0.x + w0.y * s0.y + w0.z * s0.z + w0.w * s0.w
                + w1.x * s1.x + w1.y * s1.y + w1.z * s1.z + w1.w * s1.w;
        #pragma unroll
        for (int off = 32; off > 0; off >>= 1) p += __shfl_down(p, off);
        if (lane == 0) c0[j] = 4.f * (p + bzf[j]);
    }
}

// ---- D2: [0,128) Y1 = P3@M.T + 16c | [128,192) M2 = M@M | [192,320) u ----
__global__ __launch_bounds__(256) void k_stage2(
        const float* __restrict__ M, const float* __restrict__ P3,
        const float* __restrict__ c0,
        float* __restrict__ M2, float* __restrict__ Y1, float* __restrict__ u) {
    __shared__ GemmSmem sm;
    const int b = blockIdx.x, tid = threadIdx.x;
    if (b < 128) {
        gemm_tile<2>(P3, M, Y1, c0, 16.f, (b >> 3) << 6, (b & 7) << 6, sm);
    } else if (b < 192) {
        const int bb = b - 128;
        gemm_tile<0>(M, M, M2, nullptr, 0.f, (bb >> 3) << 6, (bb & 7) << 6, sm);
    } else {
        const int j = (b - 192) * 4 + (tid >> 6);  // one output per wave
        const int lane = tid & 63, hb = lane << 3;
        const float4* mr = (const float4*)&M[(size_t)j * HD + hb];
        const float4* cr = (const float4*)&c0[hb];
        float4 m0 = mr[0], m1 = mr[1], q0 = cr[0], q1 = cr[1];
        float p = m0.x * q0.x + m0.y * q0.y + m0.z * q0.z + m0.w * q0.w
                + m1.x * q1.x + m1.y * q1.y + m1.z * q1.z + m1.w * q1.w;
        #pragma unroll
        for (int off = 32; off > 0; off >>= 1) p += __shfl_down(p, off);
        if (lane == 0) u[j] = 4.f * p + c0[j];
    }
}

// ---- D3: out = Y1 @ (M2).T + u ----
__global__ __launch_bounds__(256) void k_stage3(
        const float* __restrict__ Y1, const float* __restrict__ M2,
        const float* __restrict__ u, float* __restrict__ out) {
    __shared__ GemmSmem sm;
    const int b = blockIdx.x;
    gemm_tile<2>(Y1, M2, out, u, 1.f, (b >> 3) << 6, (b & 7) << 6, sm);
}

extern "C" void kernel_launch(void* const* d_in, const int* in_sizes, int n_in,
                              void* d_out, int out_size, void* d_ws, size_t ws_size,
                              hipStream_t stream) {
    const float* x   = (const float*)d_in[0];
    const float* Wz  = (const float*)d_in[1];
    const float* bz  = (const float*)d_in[2];
    const float* Wzf = (const float*)d_in[3];
    const float* bzf = (const float*)d_in[4];
    float* out = (float*)d_out;

    float* ws = (float*)d_ws;
    float* P3 = ws;                 // 1024*512
    float* Y1 = ws + 524288;        // 1024*512
    float* M  = ws + 1048576;       // 512*512
    float* M2 = ws + 1310720;       // 512*512
    float* c0 = ws + 1572864;       // 512
    float* u  = ws + 1573376;       // 512

    hipLaunchKernelGGL(k_stage1, dim3(1216), dim3(256), 0, stream,
                       x, Wz, Wzf, bz, bzf, P3, M, c0);
    hipLaunchKernelGGL(k_stage2, dim3(320), dim3(256), 0, stream,
                       M, P3, c0, M2, Y1, u);
    hipLaunchKernelGGL(k_stage3, dim3(128), dim3(256), 0, stream,
                       Y1, M2, u, out);
}